// Round 7
// baseline (459.314 us; speedup 1.0000x reference)
//
#include <hip/hip_runtime.h>

// CrossAttentionSpatial: GN(x), GN(condA), Q/K/V 1x1 convs, 4096x4096 attention.
// B=8, C=256, E=512, N=M=4096, GROUPS=32.
//
// R13: pipe-balanced attention. R12 was LDS-read-bound (each of 4 waves
// re-reads the same 16KB K + 16KB V tile from LDS = 128 KB/block-iter).
// Split the traffic across pipes: K stays LDS-staged (deduped, 16KB/iter,
// global_load_lds dbuf), V is read DIRECTLY from global (L2-resident: per-XCD
// K+V slice = 4MB, b = bid&7 = XCD; lane-contiguous 1KB frags, R10-verified
// pattern). LDS reads 128->64 KB/block-iter, vec 64->80 KB (under L2 ceiling).
// S/exp/permlane/PV per-wave structure and ms-split+combine verbatim R12.

typedef _Float16 half8 __attribute__((ext_vector_type(8)));
typedef _Float16 half4v __attribute__((ext_vector_type(4)));
typedef _Float16 half2v __attribute__((ext_vector_type(2)));
typedef float f32x4 __attribute__((ext_vector_type(4)));
typedef float f32x16 __attribute__((ext_vector_type(16)));
typedef unsigned u32x4v __attribute__((ext_vector_type(4)));

#define MFMA16(a, b, c) __builtin_amdgcn_mfma_f32_16x16x32_f16((a), (b), (c), 0, 0, 0)
#define MFMA32(a, b, c) __builtin_amdgcn_mfma_f32_32x32x16_f16((a), (b), (c), 0, 0, 0)

#define GLOAD_LDS(src, dst)                                                   \
  __builtin_amdgcn_global_load_lds(                                           \
      (const __attribute__((address_space(1))) unsigned*)(src),               \
      (__attribute__((address_space(3))) unsigned*)(dst), 16, 0, 0)

// ---------------------------------------------------------------------------
// Kernel 1: group stats (blocks 0..511) + weight fp32->fp16 frag-tiling
// (blocks 512..671). Wt layout: [o>>4][CIN/32 ks][64 g][8], g = (o&15) +
// 16*((k>>3)&3).
// ---------------------------------------------------------------------------
__global__ __launch_bounds__(256) void statswconv_kernel(
    const float* __restrict__ x, const float* __restrict__ condA,
    float* __restrict__ sx, float* __restrict__ sc,
    const float* __restrict__ wq, const float* __restrict__ wk,
    const float* __restrict__ wv, _Float16* __restrict__ wqt,
    _Float16* __restrict__ wkt, _Float16* __restrict__ wvt) {
  int bid = blockIdx.x;
  int t = threadIdx.x;
  if (bid >= 512) {
    int i = (bid - 512) * 256 + t;
    const float* src;
    _Float16* dst;
    int cin, ksbits, gi;
    if (i < 8192) { src = wq; dst = wqt; cin = 256; ksbits = 3; gi = i; }
    else if (i < 24576) { src = wk; dst = wkt; cin = 512; ksbits = 4; gi = i - 8192; }
    else { src = wv; dst = wvt; cin = 512; ksbits = 4; gi = i - 24576; }
    int tile = gi >> 6, g = gi & 63;
    int otile = tile >> ksbits, ks = tile & ((1 << ksbits) - 1);
    int o = otile * 16 + (g & 15), k = ks * 32 + (g >> 4) * 8;
    const float* s = src + (size_t)o * cin + k;
    half8 hv;
#pragma unroll
    for (int j = 0; j < 8; j++) hv[j] = (_Float16)s[j];
    *(half8*)(dst + (size_t)gi * 8) = hv;
    return;
  }
  const float4* src;
  int nf4;
  float* dst;
  float inv_n;
  if (bid < 256) {
    src = (const float4*)(x + (size_t)bid * 32768);
    nf4 = 8192;
    dst = sx + bid * 2;
    inv_n = 1.0f / 32768.0f;
  } else {
    int j = bid - 256;
    src = (const float4*)(condA + (size_t)j * 65536);
    nf4 = 16384;
    dst = sc + j * 2;
    inv_n = 1.0f / 65536.0f;
  }
  float s = 0.f, s2 = 0.f;
  for (int i = t; i < nf4; i += 256) {
    float4 v = src[i];
    s += v.x + v.y + v.z + v.w;
    s2 += v.x * v.x + v.y * v.y + v.z * v.z + v.w * v.w;
  }
#pragma unroll
  for (int m = 1; m <= 32; m <<= 1) {
    s += __shfl_xor(s, m, 64);
    s2 += __shfl_xor(s2, m, 64);
  }
  __shared__ float red[8];
  int w = t >> 6;
  if ((t & 63) == 0) { red[w * 2] = s; red[w * 2 + 1] = s2; }
  __syncthreads();
  if (t == 0) {
    float S = red[0] + red[2] + red[4] + red[6];
    float S2 = red[1] + red[3] + red[5] + red[7];
    float mu = S * inv_n;
    float var = S2 * inv_n - mu * mu;
    dst[0] = mu;
    dst[1] = rsqrtf(var + 1e-5f);
  }
}

// ---------------------------------------------------------------------------
// Kernel 2: normalize + transpose -> frag-tiled fp16 (both inputs, one
// launch). dst: [b][n>>4][CH/32 ks][64 g][8], g = (n&15) + 16*((c>>3)&3).
// Blocks 0..2047: x-path (CH=256); 2048..6143: condA (CH=512).
// ---------------------------------------------------------------------------
__global__ __launch_bounds__(256) void ntrans_kernel(
    const float* __restrict__ x, const float* __restrict__ condA,
    const float* __restrict__ statsx, const float* __restrict__ statsc,
    const float* __restrict__ gxw, const float* __restrict__ gxb,
    const float* __restrict__ gcw, const float* __restrict__ gcb,
    _Float16* __restrict__ hxTt, _Float16* __restrict__ h1Tt) {
  int bid = blockIdx.x;
  const float *src, *stats, *gw, *gb;
  _Float16* dst;
  int CH, gsh, bid2;
  if (bid < 2048) {
    src = x; stats = statsx; gw = gxw; gb = gxb; dst = hxTt;
    CH = 256; gsh = 3; bid2 = bid;
  } else {
    src = condA; stats = statsc; gw = gcw; gb = gcb; dst = h1Tt;
    CH = 512; gsh = 4; bid2 = bid - 2048;
  }
  int b = bid2 & 7, nt = (bid2 >> 3) & 63, ctile = bid2 >> 9;
  int n0 = nt * 64, c0 = ctile * 64;
  int t = threadIdx.x;
  __shared__ float tile[64][65];

  int cl = t >> 2;
  int c = c0 + cl;
  const float* st = stats + ((size_t)b * 32 + (c >> gsh)) * 2;
  float mu = st[0], rs = st[1];
  float a = rs * gw[c];
  float bb = gb[c] - mu * a;
  const float* srow = src + ((size_t)(b * CH + c)) * 4096 + n0 + (t & 3) * 16;
#pragma unroll
  for (int i = 0; i < 4; i++) {
    float4 v = *(const float4*)(srow + 4 * i);
    int nn = (t & 3) * 16 + 4 * i;
    tile[cl][nn + 0] = v.x * a + bb;
    tile[cl][nn + 1] = v.y * a + bb;
    tile[cl][nn + 2] = v.z * a + bb;
    tile[cl][nn + 3] = v.w * a + bb;
  }
  __syncthreads();
  int nl = t >> 2;
  half8 ov[2];
#pragma unroll
  for (int u = 0; u < 2; u++)
#pragma unroll
    for (int i = 0; i < 8; i++) ov[u][i] = (_Float16)tile[(t & 3) * 16 + 8 * u + i][nl];
  int n = n0 + nl;
  size_t tb = ((size_t)b * 256 + (n >> 4)) * (CH >> 5);
  int ca = c0 + (t & 3) * 16;
#pragma unroll
  for (int u = 0; u < 2; u++) {
    int cc = ca + 8 * u;
    size_t addr = ((tb + (cc >> 5)) * 64 + (n & 15) + 16 * ((cc >> 3) & 3)) * 8;
    *(half8*)(dst + addr) = ov[u];
  }
}

// ---------------------------------------------------------------------------
// Kernel 3: Q projection. Block = 64 n x 256 o. Stages its Ht slice (32KB,
// contiguous in tiled layout) to LDS once; all frag reads conflict-free 1KB.
// Output Qt frag-tiled: [b][n>>5][c>>4][64 g][8], g = (n&31) + 32*((c>>3)&1)
// -> per-lane 4 consecutive c = 4 consecutive j = 8B vector store.
// Grid 8*64 = 512.
// ---------------------------------------------------------------------------
__global__ __launch_bounds__(256, 2) void projQ_kernel(
    const _Float16* __restrict__ Ht, const _Float16* __restrict__ Wt,
    const float* __restrict__ bias, _Float16* __restrict__ Qt) {
  int bid = blockIdx.x;
  int b = bid & 7, nt = bid >> 3;
  int t = threadIdx.x, l = t & 63, w = t >> 6;
  int c15 = l & 15, q = l >> 4;

  __shared__ __align__(16) _Float16 hbuf[16384];  // 32KB = 4 ntiles x 8 ks
  half8* hb = (half8*)hbuf;
  {
    const half8* sg = (const half8*)Ht + (size_t)(b * 256 + nt * 4) * 512;
#pragma unroll
    for (int i = 0; i < 8; i++) hb[t + 256 * i] = sg[t + 256 * i];
  }
  __syncthreads();

  const half8* wt8 = (const half8*)Wt;
#pragma unroll
  for (int p = 0; p < 2; p++) {
    int oa = (p * 4 + w) * 2;
    f32x4 acc[2][4] = {};
#pragma unroll
    for (int ks = 0; ks < 8; ks++) {
      half8 af0 = wt8[((size_t)(oa + 0) * 8 + ks) * 64 + l];
      half8 af1 = wt8[((size_t)(oa + 1) * 8 + ks) * 64 + l];
#pragma unroll
      for (int nt2 = 0; nt2 < 4; nt2++) {
        half8 bf = hb[(nt2 * 8 + ks) * 64 + l];
        acc[0][nt2] = MFMA16(af0, bf, acc[0][nt2]);
        acc[1][nt2] = MFMA16(af1, bf, acc[1][nt2]);
      }
    }
#pragma unroll
    for (int j = 0; j < 2; j++) {
      int o4 = (oa + j) * 16 + 4 * q;
      f32x4 bv = *(const f32x4*)(bias + o4);
#pragma unroll
      for (int nt2 = 0; nt2 < 4; nt2++) {
        half4v hv;
#pragma unroll
        for (int r = 0; r < 4; r++) hv[r] = (_Float16)((acc[j][nt2][r] + bv[r]) * 0.0625f);
        size_t addr = ((((size_t)b * 128 + nt * 2 + (nt2 >> 1)) * 16 + (oa + j)) * 64 +
                       (nt2 & 1) * 16 + c15 + 32 * (q >> 1)) * 8 + (q & 1) * 4;
        *(half4v*)(Qt + addr) = hv;
      }
    }
  }
}

// ---------------------------------------------------------------------------
// Kernel 4: fused K+V projection. Block = 64 m x (256 K-o + 256 V-c). Stages
// its h1Tt slice (64KB) once; every LDS frag feeds one K-MFMA (as B-operand,
// A = Wk -> 4 consecutive o/lane -> Kt tiled store) and one V-MFMA (as
// A-operand, B = Wv -> 4 consecutive m/lane -> Vt tiled store, R3-verified
// scatter). Grid 8*64 = 512.
// ---------------------------------------------------------------------------
__global__ __launch_bounds__(256, 2) void projKV_kernel(
    const _Float16* __restrict__ Ht, const _Float16* __restrict__ Wk,
    const _Float16* __restrict__ Wv, const float* __restrict__ kb,
    const float* __restrict__ vb, _Float16* __restrict__ Kt,
    _Float16* __restrict__ Vt) {
  int bid = blockIdx.x;
  int b = bid & 7, mt = bid >> 3;
  int m0 = mt * 64;
  int t = threadIdx.x, l = t & 63, w = t >> 6;
  int c15 = l & 15, q = l >> 4;

  __shared__ __align__(16) _Float16 hbuf[32768];  // 64KB = 4 mtiles x 16 ks
  half8* hb = (half8*)hbuf;
  {
    const half8* sg = (const half8*)Ht + (size_t)(b * 256 + mt * 4) * 1024;
#pragma unroll
    for (int i = 0; i < 16; i++) hb[t + 256 * i] = sg[t + 256 * i];
  }
  __syncthreads();

  const half8* wk8 = (const half8*)Wk;
  const half8* wv8 = (const half8*)Wv;
#pragma unroll
  for (int p = 0; p < 2; p++) {
    int oa = (p * 4 + w) * 2;  // K o-tile pair == V c-tile pair
    f32x4 acck[2][4] = {};
    f32x4 accv[4][2] = {};
#pragma unroll
    for (int ks = 0; ks < 16; ks++) {
      half8 kf0 = wk8[((size_t)(oa + 0) * 16 + ks) * 64 + l];
      half8 kf1 = wk8[((size_t)(oa + 1) * 16 + ks) * 64 + l];
      half8 vf0 = wv8[((size_t)(oa + 0) * 16 + ks) * 64 + l];
      half8 vf1 = wv8[((size_t)(oa + 1) * 16 + ks) * 64 + l];
#pragma unroll
      for (int nt2 = 0; nt2 < 4; nt2++) {
        half8 lf = hb[(nt2 * 16 + ks) * 64 + l];
        acck[0][nt2] = MFMA16(kf0, lf, acck[0][nt2]);
        acck[1][nt2] = MFMA16(kf1, lf, acck[1][nt2]);
        accv[nt2][0] = MFMA16(lf, vf0, accv[nt2][0]);
        accv[nt2][1] = MFMA16(lf, vf1, accv[nt2][1]);
      }
    }
    // ---- K epilogue: Kt[b][m>>5][o>>4][g=(m&31)+32*((o>>3)&1)][j=o&7] ----
#pragma unroll
    for (int j = 0; j < 2; j++) {
      int o4 = (oa + j) * 16 + 4 * q;
      f32x4 bv = *(const f32x4*)(kb + o4);
#pragma unroll
      for (int nt2 = 0; nt2 < 4; nt2++) {
        half4v hv;
#pragma unroll
        for (int r = 0; r < 4; r++) hv[r] = (_Float16)(acck[j][nt2][r] + bv[r]);
        size_t addr = ((((size_t)b * 128 + mt * 2 + (nt2 >> 1)) * 16 + (oa + j)) * 64 +
                       (nt2 & 1) * 16 + c15 + 32 * (q >> 1)) * 8 + (q & 1) * 4;
        *(half4v*)(Kt + addr) = hv;
      }
    }
    // ---- V epilogue: verified Vt scatter (4 consecutive m per lane) ----
#pragma unroll
    for (int nt2 = 0; nt2 < 4; nt2++) {
      int m = m0 + nt2 * 16 + 4 * q;
      size_t mbase = ((size_t)b * 256 + (m >> 4)) * 8;
#pragma unroll
      for (int j = 0; j < 2; j++) {
        int c = (oa + j) * 16 + c15;
        float bs = vb[c];
        half4v hv;
#pragma unroll
        for (int r = 0; r < 4; r++) hv[r] = (_Float16)(accv[nt2][j][r] + bs);
        size_t addr = ((mbase + (c >> 5)) * 64 + (c & 31) + ((q >> 1) << 5)) * 8 + (q & 1) * 4;
        *(half4v*)(Vt + addr) = hv;
      }
    }
  }
}

// ---------------------------------------------------------------------------
// Kernel 5 (R13): pipe-balanced attention. Grid 512 = b8 x nt32 x ms2; block
// 256 thr (4 waves nh0..3), n-tile 128, KVBLK=32. K: staged to dbuf LDS
// (16KB/iter, global_load_lds) and read by all 4 waves (deduped). V: direct
// global 1KB frag loads (L2-resident per-XCD). LDS reads 64 KB/block-iter
// (half of R12); vec 80 KB. S/exp/permlane/PV verbatim R12. ms0 -> out,
// ms1 -> O1; row-sums -> l0/l1; combine unchanged.
// ---------------------------------------------------------------------------
__global__ __launch_bounds__(256, 2) void attn_kernel(
    const _Float16* __restrict__ Qt, const _Float16* __restrict__ Kt,
    const _Float16* __restrict__ Vt, float* __restrict__ out,
    float* __restrict__ O1, float* __restrict__ l0g,
    float* __restrict__ l1g) {
  int bid = blockIdx.x;
  int b = bid & 7, nt = (bid >> 3) & 31, ms = bid >> 8;
  int n0 = nt * 128;
  int t = threadIdx.x, l = t & 63, nh = t >> 6;  // 4 waves = n-quarters
  int l31 = l & 31, h = l >> 5;
  int it0 = ms * 64, it1 = it0 + 64;  // 64 of 128 m32-tiles

  __shared__ __align__(16) _Float16 kbuf[2][8192];  // 2 x 16KB K m32-tiles

  // Q B-frags in registers, held all 64 iters
  half8 qf[16];
  {
    const half8* qt8 =
        (const half8*)Qt + ((size_t)(b * 128 + nt * 4 + nh) * 16) * 64 + l;
#pragma unroll
    for (int ks = 0; ks < 16; ks++) qf[ks] = qt8[ks * 64];
  }

  const _Float16* ksrc = Kt + (size_t)b * 1048576;  // per-batch 2MB
  const half8* vg = (const half8*)(Vt + (size_t)b * 1048576) + l;

  f32x16 acc[8] = {};  // n32 x c256; c = cb*32 + l31
  float l_part = 0.f;

  // stage K(it) -> kbuf[it&1]: contiguous 16KB. 256 thr x 4 x 16B.
#define STAGE_K(it)                                                        \
  {                                                                        \
    int bs_ = (it) & 1;                                                    \
    const _Float16* ks_ = ksrc + (size_t)(it) * 8192;                      \
    _Float16* kd_ = &kbuf[bs_][0];                                         \
    _Pragma("unroll") for (int r_ = 0; r_ < 4; r_++) {                     \
      GLOAD_LDS(ks_ + (t + 256 * r_) * 8, kd_ + (t + 256 * r_) * 8);       \
    }                                                                      \
  }

  STAGE_K(it0);
  __syncthreads();  // vmcnt drained -> buf ready

  for (int it = it0; it < it1; it++) {
    int cur = it & 1;
    if (it + 1 < it1) STAGE_K(it + 1);  // async into buf[!cur]

    const half8* kb = (const half8*)&kbuf[cur][0] + l;
    const half8* vt = vg + (size_t)it * 1024;  // this iter's 16KB V tile

    // prefetch V first m16-subtile (frags u=0, cb 0..7) from global
    half8 vfA[8];
#pragma unroll
    for (int i = 0; i < 8; i++) vfA[i] = vt[i * 64];

    // ---- S^T = K Q^T (full m32 tile, k=256) ----
    f32x16 s = {};
#pragma unroll
    for (int g = 0; g < 4; g++) {
      half8 kf[4];
#pragma unroll
      for (int i = 0; i < 4; i++) kf[i] = kb[(g * 4 + i) * 64];
      __builtin_amdgcn_s_setprio(1);
#pragma unroll
      for (int i = 0; i < 4; i++) s = MFMA32(kf[i], qf[g * 4 + i], s);
      __builtin_amdgcn_s_setprio(0);
    }

    // ---- exp + row-sum + pack pairs (R10/R11/R12-verified) ----
    unsigned uo[8];
#pragma unroll
    for (int k2 = 0; k2 < 8; k2++) {
      float e0 = __expf(s[2 * k2]);
      float e1 = __expf(s[2 * k2 + 1]);
      l_part += e0 + e1;
      half2v h2 = {(_Float16)e0, (_Float16)e1};
      uo[k2] = __builtin_bit_cast(unsigned, h2);
    }
    // in-register P redistribution across lane halves (verified)
    unsigned x0 = uo[0], y0 = uo[2];
    asm("v_permlane32_swap_b32 %0, %1" : "+v"(x0), "+v"(y0));
    unsigned x1 = uo[1], y1 = uo[3];
    asm("v_permlane32_swap_b32 %0, %1" : "+v"(x1), "+v"(y1));
    unsigned x2 = uo[4], y2 = uo[6];
    asm("v_permlane32_swap_b32 %0, %1" : "+v"(x2), "+v"(y2));
    unsigned x3 = uo[5], y3 = uo[7];
    asm("v_permlane32_swap_b32 %0, %1" : "+v"(x3), "+v"(y3));
    u32x4v P0 = {x0, x1, y0, y1};  // A-frag, m_local 0..15
    u32x4v P1 = {x2, x3, y2, y3};  // A-frag, m_local 16..31
    half8 pf0 = __builtin_bit_cast(half8, P0);
    half8 pf1 = __builtin_bit_cast(half8, P1);

    // ---- O += P V: prefetch second m16-subtile, then two MFMA rounds ----
    half8 vfB[8];
#pragma unroll
    for (int i = 0; i < 8; i++) vfB[i] = vt[(8 + i) * 64];
    __builtin_amdgcn_s_setprio(1);
#pragma unroll
    for (int cb = 0; cb < 8; cb++) acc[cb] = MFMA32(pf0, vfA[cb], acc[cb]);
    __builtin_amdgcn_s_setprio(0);
    __builtin_amdgcn_s_setprio(1);
#pragma unroll
    for (int cb = 0; cb < 8; cb++) acc[cb] = MFMA32(pf1, vfB[cb], acc[cb]);
    __builtin_amdgcn_s_setprio(0);
    __syncthreads();  // STAGE_K(it+1) landed; WAR-safe for next stage
  }
#undef STAGE_K

  // ---- epilogue: unnormalized ms-partial O + partial row-sums ----
  {
    float v = l_part + __shfl_xor(l_part, 32, 64);
    float* lG = ms ? l1g : l0g;
    if (l < 32) lG[b * 4096 + n0 + nh * 32 + l] = v;
  }
  float* ob = ms ? O1 : out;
#pragma unroll
  for (int cb = 0; cb < 8; cb++) {
    int c = cb * 32 + l31;
    float* orow = ob + ((size_t)(b * 256 + c)) * 4096 + n0 + nh * 32 + 4 * h;
#pragma unroll
    for (int k2 = 0; k2 < 4; k2++) {
      f32x4 o4;
#pragma unroll
      for (int r = 0; r < 4; r++) o4[r] = acc[cb][4 * k2 + r];
      *(f32x4*)(orow + 8 * k2) = o4;
    }
  }
}

// ---------------------------------------------------------------------------
// Kernel 6: combine partials: out = (O0 + O1) / (l0 + l1).
// i indexes f32x4 over [b][c][n/4]: 8*256*4096/4 = 2,097,152 f32x4 total
// -> grid 8192 x 256. l arrays are [b][n].
// ---------------------------------------------------------------------------
__global__ __launch_bounds__(256) void combine_kernel(
    float* __restrict__ out, const float* __restrict__ O1,
    const float* __restrict__ l0g, const float* __restrict__ l1g) {
  size_t i = (size_t)blockIdx.x * 256 + threadIdx.x;
  f32x4 a = ((const f32x4*)out)[i];
  f32x4 b4 = ((const f32x4*)O1)[i];
  int bidx = (int)(i >> 18);          // 256*4096/4 f32x4 per batch
  int n4 = (int)(i & 1023);           // n/4 within row
  f32x4 La = ((const f32x4*)l0g)[bidx * 1024 + n4];
  f32x4 Lb = ((const f32x4*)l1g)[bidx * 1024 + n4];
  f32x4 r;
#pragma unroll
  for (int j = 0; j < 4; j++) r[j] = (a[j] + b4[j]) / (La[j] + Lb[j]);
  ((f32x4*)out)[i] = r;
}

// ---------------------------------------------------------------------------
extern "C" void kernel_launch(void* const* d_in, const int* in_sizes, int n_in,
                              void* d_out, int out_size, void* d_ws,
                              size_t ws_size, hipStream_t stream) {
  const float* x = (const float*)d_in[0];
  const float* condA = (const float*)d_in[1];
  const float* gxw = (const float*)d_in[2];
  const float* gxb = (const float*)d_in[3];
  const float* gcw = (const float*)d_in[4];
  const float* gcb = (const float*)d_in[5];
  const float* qw = (const float*)d_in[6];
  const float* qb = (const float*)d_in[7];
  const float* kw = (const float*)d_in[8];
  const float* kb = (const float*)d_in[9];
  const float* vw = (const float*)d_in[10];
  const float* vb = (const float*)d_in[11];
  float* out = (float*)d_out;

  char* ws = (char*)d_ws;
  float* statsx = (float*)(ws);                     // 2048 B
  float* statsc = (float*)(ws + 2048);              // 2048 B
  _Float16* wqt = (_Float16*)(ws + 4096);           // 128 KB (tiled)
  _Float16* wkt = (_Float16*)(ws + 135168);         // 256 KB (tiled)
  _Float16* wvt = (_Float16*)(ws + 397312);         // 256 KB (tiled)
  char* p = ws + 659456;
  _Float16* hxTt = (_Float16*)p; p += (size_t)8 * 4096 * 256 * 2;  // 16 MB tiled
  _Float16* h1Tt = (_Float16*)p; p += (size_t)8 * 4096 * 512 * 2;  // 32 MB tiled
  _Float16* Qt = (_Float16*)p;   p += (size_t)8 * 4096 * 256 * 2;  // 16 MB tiled
  _Float16* Kt = (_Float16*)p;   p += (size_t)8 * 4096 * 256 * 2;  // 16 MB tiled
  _Float16* Vt = (_Float16*)p;                                     // 16 MB tiled

  // Overlays (hxTt/h1Tt are dead once projQ/projKV complete):
  // O1 (33.5 MB) + l0/l1 (128 KB each) fit inside the 48 MB hxTt+h1Tt region.
  float* O1 = (float*)(ws + 659456);
  float* l0g = (float*)(ws + 659456 + (size_t)33554432);
  float* l1g = (float*)(ws + 659456 + (size_t)33554432 + 131072);

  statswconv_kernel<<<672, 256, 0, stream>>>(x, condA, statsx, statsc,
                                             qw, kw, vw, wqt, wkt, wvt);
  ntrans_kernel<<<6144, 256, 0, stream>>>(x, condA, statsx, statsc,
                                          gxw, gxb, gcw, gcb, hxTt, h1Tt);
  projQ_kernel<<<512, 256, 0, stream>>>(hxTt, wqt, qb, Qt);
  projKV_kernel<<<512, 256, 0, stream>>>(h1Tt, wkt, wvt, kb, vb, Kt, Vt);
  attn_kernel<<<512, 256, 0, stream>>>(Qt, Kt, Vt, out, O1, l0g, l1g);
  combine_kernel<<<8192, 256, 0, stream>>>(out, O1, l0g, l1g);
}

// Round 8
// 370.829 us; speedup vs baseline: 1.2386x; 1.2386x over previous
//
#include <hip/hip_runtime.h>

// CrossAttentionSpatial: GN(x), GN(condA), Q/K/V 1x1 convs, 4096x4096 attention.
// B=8, C=256, E=512, N=M=4096, GROUPS=32.
//
// R14: attn reverted to R12 (verified 151us, at LDS-read ceiling ~90 B/cyc).
// ntrans eliminated: GN + transpose fused into projQ/projKV. Each proj block
// stages its activation slice directly from x/condA (fp32), applies GN
// inline, and builds the SAME frag-tiled hbuf layout via a [64][65] fp16
// transpose tile (4 rounds Q / 8 rounds KV). MFMA + epilogues byte-identical
// to verified kernels. Saves 96 MB hxTt/h1Tt traffic + one launch.
// 5 launches: stats+wtile, projQ, projKV, attn, combine.

typedef _Float16 half8 __attribute__((ext_vector_type(8)));
typedef _Float16 half4v __attribute__((ext_vector_type(4)));
typedef _Float16 half2v __attribute__((ext_vector_type(2)));
typedef float f32x4 __attribute__((ext_vector_type(4)));
typedef float f32x16 __attribute__((ext_vector_type(16)));
typedef unsigned u32x4v __attribute__((ext_vector_type(4)));

#define MFMA16(a, b, c) __builtin_amdgcn_mfma_f32_16x16x32_f16((a), (b), (c), 0, 0, 0)
#define MFMA32(a, b, c) __builtin_amdgcn_mfma_f32_32x32x16_f16((a), (b), (c), 0, 0, 0)

#define GLOAD_LDS(src, dst)                                                   \
  __builtin_amdgcn_global_load_lds(                                           \
      (const __attribute__((address_space(1))) unsigned*)(src),               \
      (__attribute__((address_space(3))) unsigned*)(dst), 16, 0, 0)

// ---------------------------------------------------------------------------
// Kernel 1: group stats (blocks 0..511) + weight fp32->fp16 frag-tiling
// (blocks 512..671). Wt layout: [o>>4][CIN/32 ks][64 g][8], g = (o&15) +
// 16*((k>>3)&3).
// ---------------------------------------------------------------------------
__global__ __launch_bounds__(256) void statswconv_kernel(
    const float* __restrict__ x, const float* __restrict__ condA,
    float* __restrict__ sx, float* __restrict__ sc,
    const float* __restrict__ wq, const float* __restrict__ wk,
    const float* __restrict__ wv, _Float16* __restrict__ wqt,
    _Float16* __restrict__ wkt, _Float16* __restrict__ wvt) {
  int bid = blockIdx.x;
  int t = threadIdx.x;
  if (bid >= 512) {
    int i = (bid - 512) * 256 + t;
    const float* src;
    _Float16* dst;
    int cin, ksbits, gi;
    if (i < 8192) { src = wq; dst = wqt; cin = 256; ksbits = 3; gi = i; }
    else if (i < 24576) { src = wk; dst = wkt; cin = 512; ksbits = 4; gi = i - 8192; }
    else { src = wv; dst = wvt; cin = 512; ksbits = 4; gi = i - 24576; }
    int tile = gi >> 6, g = gi & 63;
    int otile = tile >> ksbits, ks = tile & ((1 << ksbits) - 1);
    int o = otile * 16 + (g & 15), k = ks * 32 + (g >> 4) * 8;
    const float* s = src + (size_t)o * cin + k;
    half8 hv;
#pragma unroll
    for (int j = 0; j < 8; j++) hv[j] = (_Float16)s[j];
    *(half8*)(dst + (size_t)gi * 8) = hv;
    return;
  }
  const float4* src;
  int nf4;
  float* dst;
  float inv_n;
  if (bid < 256) {
    src = (const float4*)(x + (size_t)bid * 32768);
    nf4 = 8192;
    dst = sx + bid * 2;
    inv_n = 1.0f / 32768.0f;
  } else {
    int j = bid - 256;
    src = (const float4*)(condA + (size_t)j * 65536);
    nf4 = 16384;
    dst = sc + j * 2;
    inv_n = 1.0f / 65536.0f;
  }
  float s = 0.f, s2 = 0.f;
  for (int i = t; i < nf4; i += 256) {
    float4 v = src[i];
    s += v.x + v.y + v.z + v.w;
    s2 += v.x * v.x + v.y * v.y + v.z * v.z + v.w * v.w;
  }
#pragma unroll
  for (int m = 1; m <= 32; m <<= 1) {
    s += __shfl_xor(s, m, 64);
    s2 += __shfl_xor(s2, m, 64);
  }
  __shared__ float red[8];
  int w = t >> 6;
  if ((t & 63) == 0) { red[w * 2] = s; red[w * 2 + 1] = s2; }
  __syncthreads();
  if (t == 0) {
    float S = red[0] + red[2] + red[4] + red[6];
    float S2 = red[1] + red[3] + red[5] + red[7];
    float mu = S * inv_n;
    float var = S2 * inv_n - mu * mu;
    dst[0] = mu;
    dst[1] = rsqrtf(var + 1e-5f);
  }
}

// ---------------------------------------------------------------------------
// Kernel 2 (R14): fused GN + transpose + Q projection. Block = (b, nt): n64 x
// o256. Phase A (4 rounds, c64 each): read x fp32, GN inline, fp16 [64][65]
// transpose tile -> frag-granule writes into hbuf (byte-identical layout to
// the old staged hxTt slice). Phase B: verified projQ MFMA + Qt epilogue.
// Grid 8*64 = 512.
// ---------------------------------------------------------------------------
__global__ __launch_bounds__(256, 2) void projQ_kernel(
    const float* __restrict__ x, const float* __restrict__ stats,
    const float* __restrict__ gw, const float* __restrict__ gb,
    const _Float16* __restrict__ Wt, const float* __restrict__ bias,
    _Float16* __restrict__ Qt) {
  int bid = blockIdx.x;
  int b = bid & 7, nt = bid >> 3;
  int n0 = nt * 64;
  int t = threadIdx.x, l = t & 63, w = t >> 6;
  int c15 = l & 15, q = l >> 4;

  __shared__ __align__(16) _Float16 hbuf[16384];  // 32KB frag-tiled slice
  __shared__ _Float16 tile[64][65];               // 8.3KB transpose buffer

  // ---- Phase A: build hbuf from x (GN fused), 4 rounds of c64 ----
  int cl = t >> 2;      // c_local within round
  int nl = t >> 2;      // n_local for granule phase
  int nn0 = (t & 3) * 16;
#pragma unroll
  for (int ct = 0; ct < 4; ct++) {
    int c0 = ct * 64;
    int c = c0 + cl;
    const float* st = stats + ((size_t)b * 32 + (c >> 3)) * 2;
    float mu = st[0], rs = st[1];
    float a = rs * gw[c];
    float bb = gb[c] - mu * a;
    const float* srow = x + ((size_t)(b * 256 + c)) * 4096 + n0 + nn0;
#pragma unroll
    for (int i = 0; i < 4; i++) {
      float4 v = *(const float4*)(srow + 4 * i);
      int nn = nn0 + 4 * i;
      tile[cl][nn + 0] = (_Float16)(v.x * a + bb);
      tile[cl][nn + 1] = (_Float16)(v.y * a + bb);
      tile[cl][nn + 2] = (_Float16)(v.z * a + bb);
      tile[cl][nn + 3] = (_Float16)(v.w * a + bb);
    }
    __syncthreads();
    int nt2 = nl >> 4, g3 = nl & 15;
#pragma unroll
    for (int u = 0; u < 2; u++) {
      int cl8 = nn0 + 8 * u;     // c_local of this 8-granule
      int c8 = c0 + cl8;
      int ks = c8 >> 5;
      int g = g3 + 16 * ((c8 >> 3) & 3);
      half8 ov;
#pragma unroll
      for (int i = 0; i < 8; i++) ov[i] = tile[cl8 + i][nl];
      *(half8*)&hbuf[(((size_t)nt2 * 8 + ks) * 64 + g) * 8] = ov;
    }
    __syncthreads();
  }

  // ---- Phase B: verified projQ MFMA + epilogue ----
  half8* hb = (half8*)hbuf;
  const half8* wt8 = (const half8*)Wt;
#pragma unroll
  for (int p = 0; p < 2; p++) {
    int oa = (p * 4 + w) * 2;
    f32x4 acc[2][4] = {};
#pragma unroll
    for (int ks = 0; ks < 8; ks++) {
      half8 af0 = wt8[((size_t)(oa + 0) * 8 + ks) * 64 + l];
      half8 af1 = wt8[((size_t)(oa + 1) * 8 + ks) * 64 + l];
#pragma unroll
      for (int nt2 = 0; nt2 < 4; nt2++) {
        half8 bf = hb[(nt2 * 8 + ks) * 64 + l];
        acc[0][nt2] = MFMA16(af0, bf, acc[0][nt2]);
        acc[1][nt2] = MFMA16(af1, bf, acc[1][nt2]);
      }
    }
#pragma unroll
    for (int j = 0; j < 2; j++) {
      int o4 = (oa + j) * 16 + 4 * q;
      f32x4 bv = *(const f32x4*)(bias + o4);
#pragma unroll
      for (int nt2 = 0; nt2 < 4; nt2++) {
        half4v hv;
#pragma unroll
        for (int r = 0; r < 4; r++) hv[r] = (_Float16)((acc[j][nt2][r] + bv[r]) * 0.0625f);
        size_t addr = ((((size_t)b * 128 + nt * 2 + (nt2 >> 1)) * 16 + (oa + j)) * 64 +
                       (nt2 & 1) * 16 + c15 + 32 * (q >> 1)) * 8 + (q & 1) * 4;
        *(half4v*)(Qt + addr) = hv;
      }
    }
  }
}

// ---------------------------------------------------------------------------
// Kernel 3 (R14): fused GN + transpose + K/V projection. Block = (b, mt):
// m64 x (256 K-o + 256 V-c). Phase A: 8 rounds of c64 build the 64KB hbuf
// (identical layout to old h1Tt slice) from condA with GN fused. Phase B:
// verified projKV MFMA + Kt/Vt epilogues. Grid 8*64 = 512.
// ---------------------------------------------------------------------------
__global__ __launch_bounds__(256, 2) void projKV_kernel(
    const float* __restrict__ condA, const float* __restrict__ stats,
    const float* __restrict__ gw, const float* __restrict__ gb,
    const _Float16* __restrict__ Wk, const _Float16* __restrict__ Wv,
    const float* __restrict__ kb, const float* __restrict__ vb,
    _Float16* __restrict__ Kt, _Float16* __restrict__ Vt) {
  int bid = blockIdx.x;
  int b = bid & 7, mt = bid >> 3;
  int m0 = mt * 64;
  int t = threadIdx.x, l = t & 63, w = t >> 6;
  int c15 = l & 15, q = l >> 4;

  __shared__ __align__(16) _Float16 hbuf[32768];  // 64KB frag-tiled slice
  __shared__ _Float16 tile[64][65];               // 8.3KB transpose buffer

  // ---- Phase A: build hbuf from condA (GN fused), 8 rounds of c64 ----
  int cl = t >> 2;
  int nl = t >> 2;
  int nn0 = (t & 3) * 16;
#pragma unroll
  for (int ct = 0; ct < 8; ct++) {
    int c0 = ct * 64;
    int c = c0 + cl;
    const float* st = stats + ((size_t)b * 32 + (c >> 4)) * 2;
    float mu = st[0], rs = st[1];
    float a = rs * gw[c];
    float bb = gb[c] - mu * a;
    const float* srow = condA + ((size_t)(b * 512 + c)) * 4096 + m0 + nn0;
#pragma unroll
    for (int i = 0; i < 4; i++) {
      float4 v = *(const float4*)(srow + 4 * i);
      int nn = nn0 + 4 * i;
      tile[cl][nn + 0] = (_Float16)(v.x * a + bb);
      tile[cl][nn + 1] = (_Float16)(v.y * a + bb);
      tile[cl][nn + 2] = (_Float16)(v.z * a + bb);
      tile[cl][nn + 3] = (_Float16)(v.w * a + bb);
    }
    __syncthreads();
    int nt2 = nl >> 4, g3 = nl & 15;
#pragma unroll
    for (int u = 0; u < 2; u++) {
      int cl8 = nn0 + 8 * u;
      int c8 = c0 + cl8;
      int ks = c8 >> 5;
      int g = g3 + 16 * ((c8 >> 3) & 3);
      half8 ov;
#pragma unroll
      for (int i = 0; i < 8; i++) ov[i] = tile[cl8 + i][nl];
      *(half8*)&hbuf[(((size_t)nt2 * 16 + ks) * 64 + g) * 8] = ov;
    }
    __syncthreads();
  }

  // ---- Phase B: verified projKV MFMA + epilogues ----
  half8* hb = (half8*)hbuf;
  const half8* wk8 = (const half8*)Wk;
  const half8* wv8 = (const half8*)Wv;
#pragma unroll
  for (int p = 0; p < 2; p++) {
    int oa = (p * 4 + w) * 2;  // K o-tile pair == V c-tile pair
    f32x4 acck[2][4] = {};
    f32x4 accv[4][2] = {};
#pragma unroll
    for (int ks = 0; ks < 16; ks++) {
      half8 kf0 = wk8[((size_t)(oa + 0) * 16 + ks) * 64 + l];
      half8 kf1 = wk8[((size_t)(oa + 1) * 16 + ks) * 64 + l];
      half8 vf0 = wv8[((size_t)(oa + 0) * 16 + ks) * 64 + l];
      half8 vf1 = wv8[((size_t)(oa + 1) * 16 + ks) * 64 + l];
#pragma unroll
      for (int nt2 = 0; nt2 < 4; nt2++) {
        half8 lf = hb[(nt2 * 16 + ks) * 64 + l];
        acck[0][nt2] = MFMA16(kf0, lf, acck[0][nt2]);
        acck[1][nt2] = MFMA16(kf1, lf, acck[1][nt2]);
        accv[nt2][0] = MFMA16(lf, vf0, accv[nt2][0]);
        accv[nt2][1] = MFMA16(lf, vf1, accv[nt2][1]);
      }
    }
    // ---- K epilogue: Kt[b][m>>5][o>>4][g=(m&31)+32*((o>>3)&1)][j=o&7] ----
#pragma unroll
    for (int j = 0; j < 2; j++) {
      int o4 = (oa + j) * 16 + 4 * q;
      f32x4 bv = *(const f32x4*)(kb + o4);
#pragma unroll
      for (int nt2 = 0; nt2 < 4; nt2++) {
        half4v hv;
#pragma unroll
        for (int r = 0; r < 4; r++) hv[r] = (_Float16)(acck[j][nt2][r] + bv[r]);
        size_t addr = ((((size_t)b * 128 + mt * 2 + (nt2 >> 1)) * 16 + (oa + j)) * 64 +
                       (nt2 & 1) * 16 + c15 + 32 * (q >> 1)) * 8 + (q & 1) * 4;
        *(half4v*)(Kt + addr) = hv;
      }
    }
    // ---- V epilogue: verified Vt scatter (4 consecutive m per lane) ----
#pragma unroll
    for (int nt2 = 0; nt2 < 4; nt2++) {
      int m = m0 + nt2 * 16 + 4 * q;
      size_t mbase = ((size_t)b * 256 + (m >> 4)) * 8;
#pragma unroll
      for (int j = 0; j < 2; j++) {
        int c = (oa + j) * 16 + c15;
        float bs = vb[c];
        half4v hv;
#pragma unroll
        for (int r = 0; r < 4; r++) hv[r] = (_Float16)(accv[nt2][j][r] + bs);
        size_t addr = ((mbase + (c >> 5)) * 64 + (c & 31) + ((q >> 1) << 5)) * 8 + (q & 1) * 4;
        *(half4v*)(Vt + addr) = hv;
      }
    }
  }
}

// ---------------------------------------------------------------------------
// Kernel 4 (= R12 verbatim, verified 151us): 2-blocks/CU attention. Grid 512
// = b8 x nt32 x ms2; block 256 thr (4 waves nh0..3), n-tile 128, KVBLK=32.
// Per iter: stage 16KB K + 16KB V into dbuf LDS (64KB total) via
// global_load_lds. Per-wave n32 x m32 S/exp/permlane/PV. ms0 -> out,
// ms1 -> O1; row-sums -> l0/l1.
// ---------------------------------------------------------------------------
__global__ __launch_bounds__(256, 2) void attn_kernel(
    const _Float16* __restrict__ Qt, const _Float16* __restrict__ Kt,
    const _Float16* __restrict__ Vt, float* __restrict__ out,
    float* __restrict__ O1, float* __restrict__ l0g,
    float* __restrict__ l1g) {
  int bid = blockIdx.x;
  int b = bid & 7, nt = (bid >> 3) & 31, ms = bid >> 8;
  int n0 = nt * 128;
  int t = threadIdx.x, l = t & 63, nh = t >> 6;  // 4 waves = n-quarters
  int l31 = l & 31, h = l >> 5;
  int it0 = ms * 64, it1 = it0 + 64;  // 64 of 128 m32-tiles

  __shared__ __align__(16) _Float16 kbuf[2][8192];  // 2 x 16KB K m32-tiles
  __shared__ __align__(16) _Float16 vbuf[2][8192];  // 2 x 16KB V m32-tiles

  // Q B-frags in registers, held all 64 iters
  half8 qf[16];
  {
    const half8* qt8 =
        (const half8*)Qt + ((size_t)(b * 128 + nt * 4 + nh) * 16) * 64 + l;
#pragma unroll
    for (int ks = 0; ks < 16; ks++) qf[ks] = qt8[ks * 64];
  }

  const _Float16* ksrc = Kt + (size_t)b * 1048576;  // per-batch 2MB
  const _Float16* vsrc = Vt + (size_t)b * 1048576;

  f32x16 acc[8] = {};  // n32 x c256; c = cb*32 + l31
  float l_part = 0.f;

#define STAGE(it)                                                          \
  {                                                                        \
    int bs_ = (it) & 1;                                                    \
    const _Float16* ks_ = ksrc + (size_t)(it) * 8192;                      \
    const _Float16* vs_ = vsrc + (size_t)(it) * 8192;                      \
    _Float16* kd_ = &kbuf[bs_][0];                                         \
    _Float16* vd_ = &vbuf[bs_][0];                                         \
    _Pragma("unroll") for (int r_ = 0; r_ < 4; r_++) {                     \
      GLOAD_LDS(ks_ + (t + 256 * r_) * 8, kd_ + (t + 256 * r_) * 8);       \
      GLOAD_LDS(vs_ + (t + 256 * r_) * 8, vd_ + (t + 256 * r_) * 8);       \
    }                                                                      \
  }

  STAGE(it0);
  __syncthreads();  // vmcnt drained -> buf ready

  for (int it = it0; it < it1; it++) {
    int cur = it & 1;
    if (it + 1 < it1) STAGE(it + 1);  // async into buf[!cur]

    const half8* kb = (const half8*)&kbuf[cur][0] + l;
    const half8* vb8 = (const half8*)&vbuf[cur][0] + l;

    // ---- S^T = K Q^T (full m32 tile, k=256) ----
    f32x16 s = {};
#pragma unroll
    for (int g = 0; g < 4; g++) {
      half8 kf[4];
#pragma unroll
      for (int i = 0; i < 4; i++) kf[i] = kb[(g * 4 + i) * 64];
      __builtin_amdgcn_s_setprio(1);
#pragma unroll
      for (int i = 0; i < 4; i++) s = MFMA32(kf[i], qf[g * 4 + i], s);
      __builtin_amdgcn_s_setprio(0);
    }

    // ---- exp + row-sum + pack pairs ----
    unsigned uo[8];
#pragma unroll
    for (int k2 = 0; k2 < 8; k2++) {
      float e0 = __expf(s[2 * k2]);
      float e1 = __expf(s[2 * k2 + 1]);
      l_part += e0 + e1;
      half2v h2 = {(_Float16)e0, (_Float16)e1};
      uo[k2] = __builtin_bit_cast(unsigned, h2);
    }
    // in-register P redistribution across lane halves (verified)
    unsigned x0 = uo[0], y0 = uo[2];
    asm("v_permlane32_swap_b32 %0, %1" : "+v"(x0), "+v"(y0));
    unsigned x1 = uo[1], y1 = uo[3];
    asm("v_permlane32_swap_b32 %0, %1" : "+v"(x1), "+v"(y1));
    unsigned x2 = uo[4], y2 = uo[6];
    asm("v_permlane32_swap_b32 %0, %1" : "+v"(x2), "+v"(y2));
    unsigned x3 = uo[5], y3 = uo[7];
    asm("v_permlane32_swap_b32 %0, %1" : "+v"(x3), "+v"(y3));
    u32x4v P0 = {x0, x1, y0, y1};  // A-frag, m_local 0..15
    u32x4v P1 = {x2, x3, y2, y3};  // A-frag, m_local 16..31
    half8 pf0 = __builtin_bit_cast(half8, P0);
    half8 pf1 = __builtin_bit_cast(half8, P1);

    // ---- O += P V (m32 tile, full c=256) ----
#pragma unroll
    for (int u = 0; u < 2; u++) {
      const half8* vv = vb8 + u * 512;  // m16 sub-tile u
      half8 pfu = u ? pf1 : pf0;
#pragma unroll
      for (int g = 0; g < 2; g++) {
        half8 vf[4];
#pragma unroll
        for (int i = 0; i < 4; i++) vf[i] = vv[(g * 4 + i) * 64];
        __builtin_amdgcn_s_setprio(1);
#pragma unroll
        for (int i = 0; i < 4; i++)
          acc[g * 4 + i] = MFMA32(pfu, vf[i], acc[g * 4 + i]);
        __builtin_amdgcn_s_setprio(0);
      }
    }
    __syncthreads();  // stage(it+1) landed; WAR-safe for stage(it+2)
  }
#undef STAGE

  // ---- epilogue: unnormalized ms-partial O + partial row-sums ----
  {
    float v = l_part + __shfl_xor(l_part, 32, 64);
    float* lG = ms ? l1g : l0g;
    if (l < 32) lG[b * 4096 + n0 + nh * 32 + l] = v;
  }
  float* ob = ms ? O1 : out;
#pragma unroll
  for (int cb = 0; cb < 8; cb++) {
    int c = cb * 32 + l31;
    float* orow = ob + ((size_t)(b * 256 + c)) * 4096 + n0 + nh * 32 + 4 * h;
#pragma unroll
    for (int k2 = 0; k2 < 4; k2++) {
      f32x4 o4;
#pragma unroll
      for (int r = 0; r < 4; r++) o4[r] = acc[cb][4 * k2 + r];
      *(f32x4*)(orow + 8 * k2) = o4;
    }
  }
}

// ---------------------------------------------------------------------------
// Kernel 5: combine partials: out = (O0 + O1) / (l0 + l1).
// i indexes f32x4 over [b][c][n/4]: 8*256*4096/4 = 2,097,152 f32x4 total
// -> grid 8192 x 256. l arrays are [b][n].
// ---------------------------------------------------------------------------
__global__ __launch_bounds__(256) void combine_kernel(
    float* __restrict__ out, const float* __restrict__ O1,
    const float* __restrict__ l0g, const float* __restrict__ l1g) {
  size_t i = (size_t)blockIdx.x * 256 + threadIdx.x;
  f32x4 a = ((const f32x4*)out)[i];
  f32x4 b4 = ((const f32x4*)O1)[i];
  int bidx = (int)(i >> 18);          // 256*4096/4 f32x4 per batch
  int n4 = (int)(i & 1023);           // n/4 within row
  f32x4 La = ((const f32x4*)l0g)[bidx * 1024 + n4];
  f32x4 Lb = ((const f32x4*)l1g)[bidx * 1024 + n4];
  f32x4 r;
#pragma unroll
  for (int j = 0; j < 4; j++) r[j] = (a[j] + b4[j]) / (La[j] + Lb[j]);
  ((f32x4*)out)[i] = r;
}

// ---------------------------------------------------------------------------
extern "C" void kernel_launch(void* const* d_in, const int* in_sizes, int n_in,
                              void* d_out, int out_size, void* d_ws,
                              size_t ws_size, hipStream_t stream) {
  const float* x = (const float*)d_in[0];
  const float* condA = (const float*)d_in[1];
  const float* gxw = (const float*)d_in[2];
  const float* gxb = (const float*)d_in[3];
  const float* gcw = (const float*)d_in[4];
  const float* gcb = (const float*)d_in[5];
  const float* qw = (const float*)d_in[6];
  const float* qb = (const float*)d_in[7];
  const float* kw = (const float*)d_in[8];
  const float* kb = (const float*)d_in[9];
  const float* vw = (const float*)d_in[10];
  const float* vb = (const float*)d_in[11];
  float* out = (float*)d_out;

  char* ws = (char*)d_ws;
  float* statsx = (float*)(ws);                     // 2048 B
  float* statsc = (float*)(ws + 2048);              // 2048 B
  _Float16* wqt = (_Float16*)(ws + 4096);           // 128 KB (tiled)
  _Float16* wkt = (_Float16*)(ws + 135168);         // 256 KB (tiled)
  _Float16* wvt = (_Float16*)(ws + 397312);         // 256 KB (tiled)
  char* p = ws + 659456;
  // R14: hxTt/h1Tt eliminated. Region layout:
  float* O1 = (float*)p;                            // 33.5 MB partial O
  float* l0g = (float*)(p + (size_t)33554432);      // 128 KB
  float* l1g = (float*)(p + (size_t)33554432 + 131072);
  _Float16* Qt = (_Float16*)(p + (size_t)33554432 + 262144);       // 16 MB
  _Float16* Kt = (_Float16*)(p + (size_t)33554432 + 262144 + 16777216);
  _Float16* Vt = (_Float16*)(p + (size_t)33554432 + 262144 + 2 * 16777216);

  statswconv_kernel<<<672, 256, 0, stream>>>(x, condA, statsx, statsc,
                                             qw, kw, vw, wqt, wkt, wvt);
  projQ_kernel<<<512, 256, 0, stream>>>(x, statsx, gxw, gxb, wqt, qb, Qt);
  projKV_kernel<<<512, 256, 0, stream>>>(condA, statsc, gcw, gcb, wkt, wvt,
                                         kb, vb, Kt, Vt);
  attn_kernel<<<512, 256, 0, stream>>>(Qt, Kt, Vt, out, O1, l0g, l1g);
  combine_kernel<<<8192, 256, 0, stream>>>(out, O1, l0g, l1g);
}